// Round 29
// baseline (65.650 us; speedup 1.0000x reference)
//
#include <hip/hip_runtime.h>
#include <utility>

#define D_DIM 256
#define WID   33
#define CEN   16
#define RACC  8                    // output rows per thread (per row-group)
#define XROWS (RACC + 2 * CEN)     // 40 x-rows read per thread per iter
#define RITER 16                   // output rows per iteration (2 rg x 8)
#define NI    16                   // iterations per block
#define CHUNK (RITER * NI)         // 256 output rows per block
#define RING  64                   // ring rows = 64 KB LDS (2 blocks/CU)
#define PROL  48                   // prologue staged rows (= RITER + 32)

// R28 (59.5us) post-mortem: LDS-pipe ~23us is the biggest non-HBM term;
// each staged row is re-read 9x ((RACC+32)/RACC at RACC=4) and only 4
// row-chains of ILP cover ds latency. This round: IDENTICAL ring/staging/
// barriers; compute reshaped to 2 col-halves x 2 row-groups x RACC=8 at
// f32x2 (ds_read_b64, 2-way bank alias = free): redundancy 9x->5x, LDS
// ~17us, readlane/output halves, 8 independent chains per wave.

typedef float f32x2 __attribute__((ext_vector_type(2)));

__device__ __forceinline__ float rdlane(float v, int l) {
    return __uint_as_float(__builtin_amdgcn_readlane(__float_as_uint(v), l));
}

__device__ __forceinline__ int clampN(int p, int N) {
    return p < 0 ? 0 : (p >= N ? N - 1 : p);
}

__device__ __forceinline__ f32x2 ld2(const float* p) {
    return *(const f32x2*)p;
}

__device__ __forceinline__ void dma_row(float* xs, int slot,
                                        const float* __restrict__ xlane,
                                        int row) {
    __builtin_amdgcn_global_load_lds(
        (const __attribute__((address_space(1))) void*)(xlane +
                                                        (size_t)row * D_DIM),
        (__attribute__((address_space(3))) void*)(xs + slot * D_DIM), 16, 0, 0);
}

template <size_t... Ss>
__device__ __forceinline__ void stage_prol(float* xs,
                                           const float* __restrict__ xlane,
                                           int base0, int N, int wv,
                                           std::index_sequence<Ss...>) {
    (([&] {
         const int s = wv * (PROL / 4) + (int)Ss;      // 12 rows per wave
         dma_row(xs, s, xlane, clampN(base0 + s, N));
     }()),
     ...);
}

// stage 16 rows (4 per wave): row n0+32+16m+k -> slot (48+16m+k) & 63
__device__ __forceinline__ void stage_iter(float* xs,
                                           const float* __restrict__ xlane,
                                           int base0, int m, int N, int wv) {
#pragma unroll
    for (int kk = 0; kk < 4; ++kk) {
        const int k = wv * 4 + kk;
        const int s = (PROL + RITER * m + k) & (RING - 1);
        dma_row(xs, s, xlane, clampN(base0 + PROL + RITER * m + k, N));
    }
}

template <size_t... Rs>
__device__ __forceinline__ void load_w(float (&w)[RACC],
                                       const float* __restrict__ smb,
                                       int nbase, int minl, int N,
                                       std::index_sequence<Rs...>) {
    ((w[Rs] = smb[(size_t)clampN(nbase + (int)Rs, N) * WID + minl]), ...);
}

template <size_t... Rs>
__device__ __forceinline__ void zero_bad_w(float (&w)[RACC], int n0w, int lane,
                                           int N, std::index_sequence<Rs...>) {
    ((w[Rs] = ((unsigned)(n0w + (int)Rs - CEN + lane) < (unsigned)N)
                  ? w[Rs] : 0.0f),
     ...);
}

template <int J, size_t... Rs>
__device__ __forceinline__ void consume_j(f32x2 (&acc)[RACC],
                                          const float (&w)[RACC], f32x2 xv,
                                          std::index_sequence<Rs...>) {
    (([&] {
         constexpr int r = (int)Rs;
         if constexpr (J - r >= 0 && J - r < WID) {
             const float ws = rdlane(w[r], J - r);
             acc[r].x = fmaf(xv.x, ws, acc[r].x);
             acc[r].y = fmaf(xv.y, ws, acc[r].y);
         }
     }()),
     ...);
}

// read row (16m + 8rg - 16 + Js) -> slot (16m + 8rg + Js) & 63
template <size_t... Js>
__device__ __forceinline__ void stream_rows(f32x2 (&acc)[RACC],
                                            const float (&w)[RACC],
                                            const float* xs, int sbase,
                                            int cp, std::index_sequence<Js...>) {
    (([&] {
         const int s = (sbase + (int)Js) & (RING - 1);
         const f32x2 xv = ld2(xs + s * D_DIM + cp);
         consume_j<(int)Js>(acc, w, xv, std::make_index_sequence<RACC>{});
     }()),
     ...);
}

template <size_t... Rs>
__device__ __forceinline__ void store_all(const f32x2 (&acc)[RACC], float szv,
                                          float* __restrict__ ob,
                                          std::index_sequence<Rs...>) {
    (([&] {
         constexpr int r = (int)Rs;
         const float inv = __builtin_amdgcn_rcpf(fmaxf(rdlane(szv, r), 1e-6f));
         f32x2 o;
         o.x = acc[r].x * inv;
         o.y = acc[r].y * inv;
         *(f32x2*)(ob + (size_t)r * D_DIM) = o;
     }()),
     ...);
}

__device__ __forceinline__ void iter_body(
    float* xs, const float* __restrict__ xlane, const float* __restrict__ smb,
    const float* __restrict__ szb, float* __restrict__ obl, int n0, int m,
    int N, int wv, int rg, int lane, int cp, float (&wcur)[RACC],
    float (&wnxt)[RACC], float& szcur, float& sznxt, int minl) {
    // phase 1: issue next-tile DMA + next-iter weight/size prefetch
    if (m < NI - 1)
        stage_iter(xs, xlane, n0 - CEN, m, N, wv);
    __builtin_amdgcn_sched_barrier(0);
    const int n1 = n0 + RITER * (m + 1) + rg * RACC;
    load_w(wnxt, smb, n1, minl, N, std::make_index_sequence<RACC>{});
    sznxt = szb[clampN(n1 + (lane & 7), N)];
    __builtin_amdgcn_sched_barrier(0);

    // phase 2: compute current 16 rows (8 per row-group) from the ring
    const int n0w = n0 + RITER * m + rg * RACC;
    if (n0w < CEN || n0w + RACC - 1 + CEN >= N)      // boundary iters only
        zero_bad_w(wcur, n0w, lane, N, std::make_index_sequence<RACC>{});

    f32x2 acc[RACC] = {};
    stream_rows(acc, wcur, xs, RITER * m + rg * RACC, cp,
                std::make_index_sequence<XROWS>{});
    store_all(acc, szcur, obl + (size_t)n0w * D_DIM,
              std::make_index_sequence<RACC>{});

    __syncthreads();   // full drain: spill-proof, ~0 cost here (R24)
}

__global__ __launch_bounds__(256) void local_enc_kernel(
    const float* __restrict__ x, const float* __restrict__ sizev,
    const float* __restrict__ sm, float* __restrict__ out, int N) {
    __shared__ float xs[RING * D_DIM];     // 64 rows x 1KB = 64 KB

    // XCD swizzle: XCD k owns batch k, strips consecutive -> L2-local
    const int bid   = blockIdx.x;
    const int swz   = (bid & 7) * 64 + (bid >> 3);
    const int strip = swz & 63;
    const int b     = swz >> 6;
    const int n0    = strip * CHUNK;
    const int tid   = threadIdx.x;
    const int wv    = tid >> 6;
    const int lane  = tid & 63;
    const int rg    = wv >> 1;             // row-group (0: rows 0-7, 1: 8-15)
    const int ch    = wv & 1;              // column half
    const int cp    = ch * 128 + lane * 2; // this thread's column pair

    const size_t bN = (size_t)b * (size_t)N;
    const float* __restrict__ xlane = x + bN * D_DIM + lane * 4;
    const float* __restrict__ smb   = sm + bN * WID;
    const float* __restrict__ szb   = sizev + bN;
    float* __restrict__ obl         = out + bN * D_DIM + cp;

    // prologue: stage first 48 rows + load iter-0 weights/sizes
    stage_prol(xs, xlane, n0 - CEN, N, wv, std::make_index_sequence<PROL / 4>{});
    const int minl = (lane < WID) ? lane : (WID - 1);
    float wA[RACC], wB[RACC];
    float szA, szB;
    load_w(wA, smb, n0 + rg * RACC, minl, N, std::make_index_sequence<RACC>{});
    szA = szb[clampN(n0 + rg * RACC + (lane & 7), N)];
    __syncthreads();

#pragma unroll 1
    for (int mp = 0; mp < NI / 2; ++mp) {
        const int m0 = 2 * mp;
        iter_body(xs, xlane, smb, szb, obl, n0, m0, N, wv, rg, lane, cp,
                  wA, wB, szA, szB, minl);
        iter_body(xs, xlane, smb, szb, obl, n0, m0 + 1, N, wv, rg, lane, cp,
                  wB, wA, szB, szA, minl);
    }
}

extern "C" void kernel_launch(void* const* d_in, const int* in_sizes, int n_in,
                              void* d_out, int out_size, void* d_ws, size_t ws_size,
                              hipStream_t stream) {
    const float* x  = (const float*)d_in[0];
    const float* sz = (const float*)d_in[1];
    const float* sm = (const float*)d_in[2];
    float* out = (float*)d_out;

    const int B = 8;
    const int N = 16384;

    dim3 grid((N / CHUNK) * B, 1, 1);   // 64 x 8 = 512 blocks, XCD-swizzled
    dim3 block(256, 1, 1);
    local_enc_kernel<<<grid, block, 0, stream>>>(x, sz, sm, out, N);
}

// Round 30
// 61.593 us; speedup vs baseline: 1.0659x; 1.0659x over previous
//
#include <hip/hip_runtime.h>
#include <utility>

#define D_DIM 256
#define BLKT  512                  // 8 waves
#define WID   33
#define CEN   16
#define RACC  8                    // output rows per thread (per wave)
#define XROWS (RACC + 2 * CEN)     // 40 x-rows read per thread per iter
#define RITER 64                   // output rows per iteration (8 waves x 8)
#define NI    8                    // iterations per block
#define CHUNK (RITER * NI)         // 512 output rows per block
#define RING  160                  // ring rows = 160 KB LDS (full CU LDS)
#define PROL  96                   // prologue staged rows (= RITER + 32)

// R29 lesson: readlane/elem scales with VECTOR WIDTH (f32x4 = 8.25/elem),
// LDS instr/elem with width AND RACC. R28 base (59.5us) was LDS-pipe-heavy:
// 2.25 b128/elem = 23us/CU. This round: RACC=8 @ f32x4 -> 1.25 b128/elem,
// barriers halve. Ring live-span = read 96 + stage 64 = 160 rows = 160KB
// (gfx950 max LDS; 128KB static proven by the 8-phase GEMM example).
// CHUNK=512 -> grid = 256 blocks = 1/CU, prologue paid exactly once.
// Slots runtime wave-uniform (R25-proven cond-subtract), arrays fold-const.

typedef float f32x4 __attribute__((ext_vector_type(4)));

__device__ __forceinline__ float rdlane(float v, int l) {
    return __uint_as_float(__builtin_amdgcn_readlane(__float_as_uint(v), l));
}

__device__ __forceinline__ int clampN(int p, int N) {
    return p < 0 ? 0 : (p >= N ? N - 1 : p);
}

__device__ __forceinline__ int modring(int s) {   // s < 2*RING
    return s >= RING ? s - RING : s;
}

__device__ __forceinline__ f32x4 ld4(const float* p) {
    return *(const f32x4*)p;
}

__device__ __forceinline__ void dma_row(float* xs, int slot,
                                        const float* __restrict__ xlane,
                                        int row) {
    __builtin_amdgcn_global_load_lds(
        (const __attribute__((address_space(1))) void*)(xlane +
                                                        (size_t)row * D_DIM),
        (__attribute__((address_space(3))) void*)(xs + slot * D_DIM), 16, 0, 0);
}

template <size_t... Ss>
__device__ __forceinline__ void stage_prol(float* xs,
                                           const float* __restrict__ xlane,
                                           int base0, int N, int wv,
                                           std::index_sequence<Ss...>) {
    (([&] {
         const int s = wv * (PROL / 8) + (int)Ss;      // 12 rows per wave
         dma_row(xs, s, xlane, clampN(base0 + s, N));
     }()),
     ...);
}

// stage 64 rows (8 per wave): row base0+96+64m+k -> slot (96+64m+k) mod 160
__device__ __forceinline__ void stage_iter(float* xs,
                                           const float* __restrict__ xlane,
                                           int base0, int m, int slot0, int N,
                                           int wv) {
    const int sb = modring(slot0 + PROL);              // < 160
#pragma unroll
    for (int kk = 0; kk < 8; ++kk) {
        const int k = wv * 8 + kk;                     // < 64
        const int s = modring(sb + k);                 // sb+k < 224 < 320
        dma_row(xs, s, xlane, clampN(base0 + PROL + RITER * m + k, N));
    }
}

template <size_t... Rs>
__device__ __forceinline__ void load_w(float (&w)[RACC],
                                       const float* __restrict__ smb,
                                       int nbase, int minl, int N,
                                       std::index_sequence<Rs...>) {
    ((w[Rs] = smb[(size_t)clampN(nbase + (int)Rs, N) * WID + minl]), ...);
}

template <size_t... Rs>
__device__ __forceinline__ void zero_bad_w(float (&w)[RACC], int n0w, int lane,
                                           int N, std::index_sequence<Rs...>) {
    ((w[Rs] = ((unsigned)(n0w + (int)Rs - CEN + lane) < (unsigned)N)
                  ? w[Rs] : 0.0f),
     ...);
}

template <int J, size_t... Rs>
__device__ __forceinline__ void consume_j(f32x4 (&acc)[RACC],
                                          const float (&w)[RACC], f32x4 xv,
                                          std::index_sequence<Rs...>) {
    (([&] {
         constexpr int r = (int)Rs;
         if constexpr (J - r >= 0 && J - r < WID) {
             const float ws = rdlane(w[r], J - r);
             acc[r].x = fmaf(xv.x, ws, acc[r].x);
             acc[r].y = fmaf(xv.y, ws, acc[r].y);
             acc[r].z = fmaf(xv.z, ws, acc[r].z);
             acc[r].w = fmaf(xv.w, ws, acc[r].w);
         }
     }()),
     ...);
}

// wave wv, iter m: read x rows rel-base0 (64m+8wv .. +39) -> slots
// (slot0 + 8wv + Js) mod 160, sbase < 216, +39 < 320: one cond-subtract
template <size_t... Js>
__device__ __forceinline__ void stream_rows(f32x4 (&acc)[RACC],
                                            const float (&w)[RACC],
                                            const float* xs, int sbase,
                                            int lane4,
                                            std::index_sequence<Js...>) {
    (([&] {
         const int s = modring(sbase + (int)Js);
         const f32x4 xv = ld4(xs + s * D_DIM + lane4);
         consume_j<(int)Js>(acc, w, xv, std::make_index_sequence<RACC>{});
     }()),
     ...);
}

template <size_t... Rs>
__device__ __forceinline__ void store_all(const f32x4 (&acc)[RACC], float szv,
                                          float* __restrict__ ob,
                                          std::index_sequence<Rs...>) {
    (([&] {
         constexpr int r = (int)Rs;
         const float inv = __builtin_amdgcn_rcpf(fmaxf(rdlane(szv, r), 1e-6f));
         f32x4 o;
         o.x = acc[r].x * inv; o.y = acc[r].y * inv;
         o.z = acc[r].z * inv; o.w = acc[r].w * inv;
         *(f32x4*)(ob + (size_t)r * D_DIM) = o;
     }()),
     ...);
}

__device__ __forceinline__ void iter_body(
    float* xs, const float* __restrict__ xlane, const float* __restrict__ smb,
    const float* __restrict__ szb, float* __restrict__ obl, int n0, int m,
    int slot0, int N, int wv, int lane, int lane4, float (&wcur)[RACC],
    float (&wnxt)[RACC], float& szcur, float& sznxt, int minl) {
    // phase 1: issue next-tile DMA + next-iter weight/size prefetch
    if (m < NI - 1)
        stage_iter(xs, xlane, n0 - CEN, m, slot0, N, wv);
    __builtin_amdgcn_sched_barrier(0);
    const int n1 = n0 + RITER * (m + 1) + wv * RACC;
    load_w(wnxt, smb, n1, minl, N, std::make_index_sequence<RACC>{});
    sznxt = szb[clampN(n1 + (lane & 7), N)];
    __builtin_amdgcn_sched_barrier(0);

    // phase 2: compute current 64 rows (8 per wave) from the ring
    const int n0w = n0 + RITER * m + wv * RACC;
    if (n0w < CEN || n0w + RACC - 1 + CEN >= N)      // boundary iters only
        zero_bad_w(wcur, n0w, lane, N, std::make_index_sequence<RACC>{});

    f32x4 acc[RACC] = {};
    stream_rows(acc, wcur, xs, slot0 + wv * RACC, lane4,
                std::make_index_sequence<XROWS>{});
    store_all(acc, szcur, obl + (size_t)n0w * D_DIM,
              std::make_index_sequence<RACC>{});

    __syncthreads();   // full drain: spill-proof, ~0 cost here (R24)
}

__global__ __launch_bounds__(BLKT) void local_enc_kernel(
    const float* __restrict__ x, const float* __restrict__ sizev,
    const float* __restrict__ sm, float* __restrict__ out, int N) {
    __shared__ float xs[RING * D_DIM];     // 160 rows x 1KB = 160 KB

    // XCD swizzle: XCD k owns batch k, strips consecutive -> L2-local
    const int bid   = blockIdx.x;
    const int swz   = (bid & 7) * 32 + (bid >> 3);
    const int strip = swz & 31;
    const int b     = swz >> 5;
    const int n0    = strip * CHUNK;
    const int tid   = threadIdx.x;
    const int wv    = tid >> 6;            // 0..7 -> row-group
    const int lane  = tid & 63;
    const int lane4 = lane * 4;            // this thread's 4 columns

    const size_t bN = (size_t)b * (size_t)N;
    const float* __restrict__ xlane = x + bN * D_DIM + lane4;
    const float* __restrict__ smb   = sm + bN * WID;
    const float* __restrict__ szb   = sizev + bN;
    float* __restrict__ obl         = out + bN * D_DIM + lane4;

    // prologue: stage first 96 rows + load iter-0 weights/sizes
    stage_prol(xs, xlane, n0 - CEN, N, wv, std::make_index_sequence<PROL / 8>{});
    const int minl = (lane < WID) ? lane : (WID - 1);
    float wA[RACC], wB[RACC];
    float szA, szB;
    load_w(wA, smb, n0 + wv * RACC, minl, N, std::make_index_sequence<RACC>{});
    szA = szb[clampN(n0 + wv * RACC + (lane & 7), N)];
    __syncthreads();

    int slot0 = 0;
#pragma unroll 1
    for (int mp = 0; mp < NI / 2; ++mp) {
        const int m0 = 2 * mp;
        iter_body(xs, xlane, smb, szb, obl, n0, m0, slot0, N, wv, lane, lane4,
                  wA, wB, szA, szB, minl);
        slot0 = modring(slot0 + RITER);
        iter_body(xs, xlane, smb, szb, obl, n0, m0 + 1, slot0, N, wv, lane,
                  lane4, wB, wA, szB, szA, minl);
        slot0 = modring(slot0 + RITER);
    }
}

extern "C" void kernel_launch(void* const* d_in, const int* in_sizes, int n_in,
                              void* d_out, int out_size, void* d_ws, size_t ws_size,
                              hipStream_t stream) {
    const float* x  = (const float*)d_in[0];
    const float* sz = (const float*)d_in[1];
    const float* sm = (const float*)d_in[2];
    float* out = (float*)d_out;

    const int B = 8;
    const int N = 16384;

    dim3 grid((N / CHUNK) * B, 1, 1);   // 32 x 8 = 256 blocks = 1 per CU
    dim3 block(BLKT, 1, 1);
    local_enc_kernel<<<grid, block, 0, stream>>>(x, sz, sm, out, N);
}